// Round 1
// 149.666 us; speedup vs baseline: 1.0016x; 1.0016x over previous
//
#include <hip/hip_runtime.h>
#include <hip/hip_bf16.h>
#include <hip/hip_fp16.h>

#define N_NODES 100000
#define D 64
#define N_EDGES 1250000

// fine buckets (sortgather granularity)
#define RB 64                   // nodes per fine bucket (dst>>6)
#define NB 1563                 // ceil(N / 64)
#define FCAP 1536               // fine slab capacity; mean 800, max ~950
#define SORT_CAP 1536

// coarse buckets (partition pass A)
#define CB_SHIFT 11             // 2048 nodes per coarse bucket
#define NCB 49                  // ceil(N / 2048)
#define CCAP 28672              // mean 25510, sigma ~158 -> +20 sigma
#define FINE_PER_COARSE 32      // 2048/64

#define EPB 2048                // edges per pass-A block (was 8192: long LDS-atomic tail)
#define PARTA_BLOCKS ((N_EDGES + EPB - 1) / EPB)   // 611
#define SEGS 16                 // pass-B blocks per coarse bucket (was 8)

#define TN 64                   // nodes per pre block
#define PRE_BLOCKS 1563         // ceil(N / 64)
#define FUSED_BLOCKS (PARTA_BLOCKS + PRE_BLOCKS)

#define XP 72                   // LDS fp16 row stride (64 + 8 pad -> 2-way-free b128)

typedef unsigned short ushort_t;
typedef _Float16 half_t;
typedef __attribute__((ext_vector_type(8))) _Float16 half8;
typedef __attribute__((ext_vector_type(4))) float floatx4;

// ---------------------------------------------------------------------------
// Fused pre-transform + partition pass A (one dispatch; partA's 611 blocks
// hide inside pre).
//
// pre role (blocks PARTA_BLOCKS..): [Y|Z] = X @ [W_l|W_r] via fp16 MFMA
//   (mfma_f32_16x16x32_f16, fp32 accumulate). Aggregation commutes with the
//   linear map: (sum x_j)@W_l = sum (x_j@W_l).
//   Fragment maps: A[m=lane&15][k=quad*8+j], B[k=quad*8+j][n=lane&15],
//   C/D col=lane&15 row=quad*4+reg (dtype-independent).
// partA role (blocks 0..PARTA_BLOCKS-1): scatter edges into 49 coarse
//   buckets (dst>>11). Round-0 (this session): 8192-edge blocks serialized on
//   two passes of LDS atomics over 49 counters shared by 4 waves -> 40 us
//   low-occupancy tail (Occ 18.5%, 1.9M bank-conflict cycles). Now 2048-edge
//   blocks + per-wave privatized histograms: atomics only collide within a
//   wave (64 lanes / 49 counters ~= 1.3x multiplicity).
// Cursors zeroed by a 6.5 KB hipMemsetAsync before this dispatch.
// ---------------------------------------------------------------------------
__global__ __launch_bounds__(256) void pre_part_kernel(
    const float* __restrict__ x, const float* __restrict__ W_l,
    const float* __restrict__ b_l, const float* __restrict__ W_r,
    ushort_t* __restrict__ y, ushort_t* __restrict__ z,
    const int* __restrict__ src, const int* __restrict__ dst,
    int* __restrict__ ccursor, unsigned* __restrict__ coarse,
    int N, int E)
{
    int t = threadIdx.x;

    if (blockIdx.x < PARTA_BLOCKS) {
        // ---------------- partA role ----------------
        __shared__ int hist[4][NCB];    // per-wave private histograms
        __shared__ int wbase[4][NCB];   // per-wave write bases
        const int w = t >> 6;

        if (t < 4 * NCB) ((int*)hist)[t] = 0;
        __syncthreads();

        int base = blockIdx.x * EPB;
        int lim = E - base; if (lim > EPB) lim = EPB;

        for (int i = t; i < lim; i += 256) {
            int d = dst[base + i];
            atomicAdd(&hist[w][d >> CB_SHIFT], 1);
        }
        __syncthreads();

        if (t < NCB) {
            int c0 = hist[0][t], c1 = hist[1][t];
            int c2 = hist[2][t], c3 = hist[3][t];
            int tot = c0 + c1 + c2 + c3;
            int b0 = tot ? atomicAdd(&ccursor[t], tot) : 0;
            wbase[0][t] = b0;
            wbase[1][t] = b0 + c0;
            wbase[2][t] = b0 + c0 + c1;
            wbase[3][t] = b0 + c0 + c1 + c2;
        }
        __syncthreads();

        for (int i = t; i < lim; i += 256) {
            int d = dst[base + i];
            int s = src[base + i];
            int b = d >> CB_SHIFT;
            int pos = atomicSub(&hist[w][b], 1) - 1;
            coarse[(size_t)b * CCAP + wbase[w][b] + pos] =
                (unsigned)s | ((unsigned)(d & ((1 << CB_SHIFT) - 1)) << 17);
        }
        return;
    }

    // ---------------- pre role (MFMA) ----------------
    __shared__ half_t sWt[128 * XP];   // sWt[col][k] = W[k][col], 18,432 B
    __shared__ half_t sXh[TN * XP];    // sXh[node][k] fp16,        9,216 B

    // stage W transposed fp16 (W_l -> cols 0..63, W_r -> cols 64..127)
    for (int i = t; i < 64 * 64; i += 256) {
        int k = i >> 6, c = i & 63;
        sWt[c * XP + k]        = (half_t)W_l[i];
        sWt[(64 + c) * XP + k] = (half_t)W_r[i];
    }

    long base = (long)(blockIdx.x - PARTA_BLOCKS) * TN;
    for (int i = t; i < TN * 16; i += 256) {   // 64 nodes x 16 float4
        int n = i >> 4, q = i & 15;
        long node = base + n;
        float4 v = make_float4(0.f, 0.f, 0.f, 0.f);
        if (node < N) v = ((const float4*)(x + node * D))[q];
        half_t* p = &sXh[n * XP + q * 4];
        p[0] = (half_t)v.x; p[1] = (half_t)v.y;
        p[2] = (half_t)v.z; p[3] = (half_t)v.w;
    }
    __syncthreads();

    const int lane  = t & 63;
    const int w     = t >> 6;        // wave id = node-tile 0..3
    const int col16 = lane & 15;
    const int quad  = lane >> 4;

    // A fragments (this wave's 16 nodes), k-chunks 0..31 / 32..63
    const int nrow = w * 16 + col16;             // m = lane&15
    half8 a0 = *(half8*)&sXh[nrow * XP + quad * 8];
    half8 a1 = *(half8*)&sXh[nrow * XP + 32 + quad * 8];

    float bias[4];
#pragma unroll
    for (int j = 0; j < 4; j++) bias[j] = b_l[j * 16 + col16];

    long nodeBase = base + w * 16;

#pragma unroll 2
    for (int ct = 0; ct < 8; ct++) {
        int c = ct * 16 + col16;                 // n = lane&15
        half8 b0 = *(half8*)&sWt[c * XP + quad * 8];
        half8 b1 = *(half8*)&sWt[c * XP + 32 + quad * 8];
        floatx4 acc = {0.f, 0.f, 0.f, 0.f};
        acc = __builtin_amdgcn_mfma_f32_16x16x32_f16(a0, b0, acc, 0, 0, 0);
        acc = __builtin_amdgcn_mfma_f32_16x16x32_f16(a1, b1, acc, 0, 0, 0);

        ushort_t* obuf = (ct < 4) ? y : z;
        int cc    = (ct < 4) ? c : (c - 64);
        float badd = (ct < 4) ? 0.f : bias[ct - 4];
#pragma unroll
        for (int r = 0; r < 4; r++) {
            long node = nodeBase + quad * 4 + r;   // row = quad*4 + reg
            if (node < N) {
                half_t hv = (half_t)(acc[r] + badd);
                obuf[node * D + cc] = *(ushort_t*)&hv;
            }
        }
    }
}

// ---------------------------------------------------------------------------
// Partition pass B: 16 segment-blocks per coarse bucket. Scatters into the 32
// fine buckets inside the coarse bucket. Per-wave privatized histograms
// (same fix as partA: cross-wave same-address LDS atomic serialization was
// the critical path). Repacks src | fineLocal<<17.
// ---------------------------------------------------------------------------
__global__ __launch_bounds__(256) void partB_kernel(
    const unsigned* __restrict__ coarse, const int* __restrict__ ccursor,
    int* __restrict__ fcursor, unsigned* __restrict__ fine)
{
    __shared__ int hist[4][FINE_PER_COARSE];
    __shared__ int wbase[4][FINE_PER_COARSE];
    int cb = blockIdx.x >> 4;        // SEGS = 16
    int seg = blockIdx.x & 15;
    int t = threadIdx.x;
    const int w = t >> 6;

    int cnt = ccursor[cb];
    int segLen = (cnt + SEGS - 1) / SEGS;
    int beg = seg * segLen;
    int end = beg + segLen; if (end > cnt) end = cnt;

    if (t < 4 * FINE_PER_COARSE) ((int*)hist)[t] = 0;
    __syncthreads();

    const unsigned* __restrict__ slab = coarse + (size_t)cb * CCAP;

    for (int i = beg + t; i < end; i += 256) {
        unsigned e = slab[i];
        atomicAdd(&hist[w][(e >> 17) >> 6], 1);
    }
    __syncthreads();

    if (t < FINE_PER_COARSE) {
        int c0 = hist[0][t], c1 = hist[1][t];
        int c2 = hist[2][t], c3 = hist[3][t];
        int tot = c0 + c1 + c2 + c3;
        int fb = cb * FINE_PER_COARSE + t;
        int b0 = tot ? atomicAdd(&fcursor[fb], tot) : 0;
        wbase[0][t] = b0;
        wbase[1][t] = b0 + c0;
        wbase[2][t] = b0 + c0 + c1;
        wbase[3][t] = b0 + c0 + c1 + c2;
    }
    __syncthreads();

    for (int i = beg + t; i < end; i += 256) {
        unsigned e = slab[i];
        unsigned cl = e >> 17;
        int fb_loc = cl >> 6;
        int pos = atomicSub(&hist[w][fb_loc], 1) - 1;
        size_t fb = (size_t)cb * FINE_PER_COARSE + fb_loc;
        fine[fb * FCAP + wbase[w][fb_loc] + pos] =
            (e & 0x1FFFFu) | ((cl & 63u) << 17);
    }
}

// ---------------------------------------------------------------------------
// Fused sort + gather: one 512-thread block per fine bucket.
// Sort: slab entries staged in registers (<=3/thread), LDS int-atomic
//       counting sort over 64 local nodes (round-5 lesson: int atomics only).
//       Prefix scan is now a single-wave __shfl_up scan (1 barrier, was 12).
// Gather: 8 lanes per node; lane loads uint4 (8 fp16 feats) -> one wave-instr
//       = 8 rows x 128 B = 1024 B. 4-edge unroll for MLP (latency-bound).
// Epilogue: out = tanh(acc + z), z fp16 from ws.
// ---------------------------------------------------------------------------
__global__ __launch_bounds__(512) void sortgather_kernel(
    const ushort_t* __restrict__ y, const ushort_t* __restrict__ z,
    const unsigned* __restrict__ part, const int* __restrict__ cursor,
    float* __restrict__ out, int N)
{
    __shared__ int sorted[SORT_CAP];
    __shared__ int hist[RB];
    __shared__ int cur[RB];
    __shared__ int begL[RB];

    int b = blockIdx.x;
    int t = threadIdx.x;
    int cnt = cursor[b];
    if (cnt > SORT_CAP) cnt = SORT_CAP;   // unreachable (max ~950)
    const unsigned* __restrict__ slab = part + (size_t)b * FCAP;

    // stage slab entries in registers (SORT_CAP = 3*512)
    unsigned e0 = 0, e1 = 0, e2 = 0;
    int i0 = t, i1 = t + 512, i2 = t + 1024;
    if (i0 < cnt) e0 = slab[i0];
    if (i1 < cnt) e1 = slab[i1];
    if (i2 < cnt) e2 = slab[i2];

    if (t < RB) hist[t] = 0;
    __syncthreads();

    if (i0 < cnt) atomicAdd(&hist[e0 >> 17], 1);
    if (i1 < cnt) atomicAdd(&hist[e1 >> 17], 1);
    if (i2 < cnt) atomicAdd(&hist[e2 >> 17], 1);
    __syncthreads();

    // exclusive prefix over 64 counters: wave-0 shfl scan, no barriers inside
    if (t < RB) {
        int v = hist[t];
        int inc = v;
#pragma unroll
        for (int off = 1; off < RB; off <<= 1) {
            int n = __shfl_up(inc, off, RB);
            if (t >= off) inc += n;
        }
        int ex = inc - v;
        cur[t] = ex;
        begL[t] = ex;
    }
    __syncthreads();

    if (i0 < cnt) { int p = atomicAdd(&cur[e0 >> 17], 1); sorted[p] = (int)(e0 & 0x1FFFF); }
    if (i1 < cnt) { int p = atomicAdd(&cur[e1 >> 17], 1); sorted[p] = (int)(e1 & 0x1FFFF); }
    if (i2 < cnt) { int p = atomicAdd(&cur[e2 >> 17], 1); sorted[p] = (int)(e2 & 0x1FFFF); }
    __syncthreads();

    // ---- gather phase: group g (8 lanes) owns node g ----
    const int g = t >> 3;     // local node 0..63
    const int f = t & 7;      // feature slice: halves 8f..8f+7
    int myBeg = begL[g];
    int myDeg = hist[g];

    float2 acc0 = make_float2(0.f, 0.f), acc1 = acc0, acc2 = acc0, acc3 = acc0;

    int i = 0;
    for (; i + 4 <= myDeg; i += 4) {
        int s0 = sorted[myBeg + i];
        int s1 = sorted[myBeg + i + 1];
        int s2 = sorted[myBeg + i + 2];
        int s3 = sorted[myBeg + i + 3];
        uint4 r0 = ((const uint4*)(y + (size_t)s0 * D))[f];
        uint4 r1 = ((const uint4*)(y + (size_t)s1 * D))[f];
        uint4 r2 = ((const uint4*)(y + (size_t)s2 * D))[f];
        uint4 r3 = ((const uint4*)(y + (size_t)s3 * D))[f];
#define ACC(r) { \
        float2 c0 = __half22float2(*(const __half2*)&(r).x); \
        float2 c1 = __half22float2(*(const __half2*)&(r).y); \
        float2 c2 = __half22float2(*(const __half2*)&(r).z); \
        float2 c3 = __half22float2(*(const __half2*)&(r).w); \
        acc0.x += c0.x; acc0.y += c0.y; acc1.x += c1.x; acc1.y += c1.y; \
        acc2.x += c2.x; acc2.y += c2.y; acc3.x += c3.x; acc3.y += c3.y; }
        ACC(r0) ACC(r1) ACC(r2) ACC(r3)
    }
    for (; i < myDeg; i++) {
        int s = sorted[myBeg + i];
        uint4 r = ((const uint4*)(y + (size_t)s * D))[f];
        ACC(r)
    }
#undef ACC

    long gn = (long)b * RB + g;
    if (gn < N) {
        uint4 zr = ((const uint4*)(z + (size_t)gn * D))[f];
        float2 z0 = __half22float2(*(const __half2*)&zr.x);
        float2 z1 = __half22float2(*(const __half2*)&zr.y);
        float2 z2 = __half22float2(*(const __half2*)&zr.z);
        float2 z3 = __half22float2(*(const __half2*)&zr.w);
        float4 o0, o1;
        o0.x = tanhf(acc0.x + z0.x); o0.y = tanhf(acc0.y + z0.y);
        o0.z = tanhf(acc1.x + z1.x); o0.w = tanhf(acc1.y + z1.y);
        o1.x = tanhf(acc2.x + z2.x); o1.y = tanhf(acc2.y + z2.y);
        o1.z = tanhf(acc3.x + z3.x); o1.w = tanhf(acc3.y + z3.y);
        float4* op = (float4*)(out + gn * D);
        op[2 * f] = o0;
        op[2 * f + 1] = o1;
    }
}

extern "C" void kernel_launch(void* const* d_in, const int* in_sizes, int n_in,
                              void* d_out, int out_size, void* d_ws, size_t ws_size,
                              hipStream_t stream) {
    const float* x   = (const float*)d_in[0];
    const int* ei    = (const int*)d_in[1];   // [2,E] int32
    const float* W_l = (const float*)d_in[2];
    const float* b_l = (const float*)d_in[3];
    const float* W_r = (const float*)d_in[4];
    float* out = (float*)d_out;

    const int N = N_NODES;
    const int E = N_EDGES;
    const int* src = ei;
    const int* dst = ei + E;

    // workspace layout (total ~40.8 MB; ws is 268 MB)
    char* ws = (char*)d_ws;
    ushort_t* y      = (ushort_t*)(ws);                  // 12,800,000 B
    ushort_t* z      = (ushort_t*)(ws + 12800000);       // 12,800,000 B
    unsigned* coarse = (unsigned*)(ws + 25600000);       // NCB*CCAP*4 = 5,619,712 B
    unsigned* fine   = (unsigned*)(ws + 31219712);       // NB*FCAP*4 = 9,603,072 B
    int* ccursor     = (int*)(ws + 40822784);            // 196 B (padded to 256)
    int* fcursor     = (int*)(ws + 40823040);            // NB*4 = 6,252 B

    // zero both cursor arrays (adjacent): 256 + 6252 bytes
    hipMemsetAsync(ccursor, 0, 6508, stream);

    pre_part_kernel<<<FUSED_BLOCKS, 256, 0, stream>>>(
        x, W_l, b_l, W_r, y, z, src, dst, ccursor, coarse, N, E);
    partB_kernel<<<NCB * SEGS, 256, 0, stream>>>(coarse, ccursor, fcursor, fine);
    sortgather_kernel<<<NB, 512, 0, stream>>>(y, z, fine, fcursor, out, N);
}

// Round 2
// 144.211 us; speedup vs baseline: 1.0395x; 1.0378x over previous
//
#include <hip/hip_runtime.h>
#include <hip/hip_bf16.h>
#include <hip/hip_fp16.h>

#define N_NODES 100000
#define D 64
#define N_EDGES 1250000

// fine buckets (sortgather granularity)
#define RB 64                   // nodes per fine bucket (dst>>6)
#define NB 1563                 // ceil(N / 64)
#define FCAP 1536               // fine slab capacity; mean 800, max ~950
#define SORT_CAP 1536

// coarse buckets (partition pass A)
#define CB_SHIFT 11             // 2048 nodes per coarse bucket
#define NCB 49                  // ceil(N / 2048)
#define CCAP 28672              // mean 25510, sigma ~158 -> +20 sigma
#define FINE_PER_COARSE 32      // 2048/64

// cursor padding: one counter per 64B cache line. Round-1 lesson: 49 packed
// cursors = 4 cache lines; every partA block fires 49 global atomicAdds at
// those 4 lines -> L2 same-line atomic serialization -> blocks parked at
// __syncthreads -> 42.7us dispatch with all pipes idle (Occ 18.5%).
#define CPAD 16                 // ints per cursor slot (64 B)

#define EPB 8192                // edges per pass-A block (back to 8192: fewer
                                // global atomics per line + longer write runs)
#define PARTA_BLOCKS ((N_EDGES + EPB - 1) / EPB)   // 153
#define SEGS 16                 // pass-B blocks per coarse bucket

#define TN 64                   // nodes per pre block
#define PRE_BLOCKS 1563         // ceil(N / 64)
#define FUSED_BLOCKS (PARTA_BLOCKS + PRE_BLOCKS)

#define XP 72                   // LDS fp16 row stride (64 + 8 pad -> 2-way-free b128)

typedef unsigned short ushort_t;
typedef _Float16 half_t;
typedef __attribute__((ext_vector_type(8))) _Float16 half8;
typedef __attribute__((ext_vector_type(4))) float floatx4;

// ---------------------------------------------------------------------------
// Fused pre-transform + partition pass A (one dispatch; partA's 153 blocks
// hide inside pre).
//
// pre role (blocks PARTA_BLOCKS..): [Y|Z] = X @ [W_l|W_r] via fp16 MFMA
//   (mfma_f32_16x16x32_f16, fp32 accumulate). Aggregation commutes with the
//   linear map: (sum x_j)@W_l = sum (x_j@W_l).
//   Fragment maps: A[m=lane&15][k=quad*8+j], B[k=quad*8+j][n=lane&15],
//   C/D col=lane&15 row=quad*4+reg (dtype-independent).
// partA role (blocks 0..PARTA_BLOCKS-1): scatter edges into 49 coarse
//   buckets (dst>>11). Per-wave privatized LDS histograms; ONE padded global
//   atomicAdd per (block, bucket) -> 153 atomics per cursor line.
// Cursors zeroed by a ~103 KB hipMemsetAsync before this dispatch.
// ---------------------------------------------------------------------------
__global__ __launch_bounds__(256) void pre_part_kernel(
    const float* __restrict__ x, const float* __restrict__ W_l,
    const float* __restrict__ b_l, const float* __restrict__ W_r,
    ushort_t* __restrict__ y, ushort_t* __restrict__ z,
    const int* __restrict__ src, const int* __restrict__ dst,
    int* __restrict__ ccursor, unsigned* __restrict__ coarse,
    int N, int E)
{
    int t = threadIdx.x;

    if (blockIdx.x < PARTA_BLOCKS) {
        // ---------------- partA role ----------------
        __shared__ int hist[4][NCB];    // per-wave private histograms
        __shared__ int wbase[4][NCB];   // per-wave write bases
        const int w = t >> 6;

        if (t < 4 * NCB) ((int*)hist)[t] = 0;
        __syncthreads();

        int base = blockIdx.x * EPB;
        int lim = E - base; if (lim > EPB) lim = EPB;

        for (int i = t; i < lim; i += 256) {
            int d = dst[base + i];
            atomicAdd(&hist[w][d >> CB_SHIFT], 1);
        }
        __syncthreads();

        if (t < NCB) {
            int c0 = hist[0][t], c1 = hist[1][t];
            int c2 = hist[2][t], c3 = hist[3][t];
            int tot = c0 + c1 + c2 + c3;
            int b0 = tot ? atomicAdd(&ccursor[t * CPAD], tot) : 0;
            wbase[0][t] = b0;
            wbase[1][t] = b0 + c0;
            wbase[2][t] = b0 + c0 + c1;
            wbase[3][t] = b0 + c0 + c1 + c2;
        }
        __syncthreads();

        for (int i = t; i < lim; i += 256) {
            int d = dst[base + i];
            int s = src[base + i];
            int b = d >> CB_SHIFT;
            int pos = atomicSub(&hist[w][b], 1) - 1;
            coarse[(size_t)b * CCAP + wbase[w][b] + pos] =
                (unsigned)s | ((unsigned)(d & ((1 << CB_SHIFT) - 1)) << 17);
        }
        return;
    }

    // ---------------- pre role (MFMA) ----------------
    __shared__ half_t sWt[128 * XP];   // sWt[col][k] = W[k][col], 18,432 B
    __shared__ half_t sXh[TN * XP];    // sXh[node][k] fp16,        9,216 B

    // stage W transposed fp16 (W_l -> cols 0..63, W_r -> cols 64..127)
    for (int i = t; i < 64 * 64; i += 256) {
        int k = i >> 6, c = i & 63;
        sWt[c * XP + k]        = (half_t)W_l[i];
        sWt[(64 + c) * XP + k] = (half_t)W_r[i];
    }

    long base = (long)(blockIdx.x - PARTA_BLOCKS) * TN;
    for (int i = t; i < TN * 16; i += 256) {   // 64 nodes x 16 float4
        int n = i >> 4, q = i & 15;
        long node = base + n;
        float4 v = make_float4(0.f, 0.f, 0.f, 0.f);
        if (node < N) v = ((const float4*)(x + node * D))[q];
        half_t* p = &sXh[n * XP + q * 4];
        p[0] = (half_t)v.x; p[1] = (half_t)v.y;
        p[2] = (half_t)v.z; p[3] = (half_t)v.w;
    }
    __syncthreads();

    const int lane  = t & 63;
    const int w     = t >> 6;        // wave id = node-tile 0..3
    const int col16 = lane & 15;
    const int quad  = lane >> 4;

    // A fragments (this wave's 16 nodes), k-chunks 0..31 / 32..63
    const int nrow = w * 16 + col16;             // m = lane&15
    half8 a0 = *(half8*)&sXh[nrow * XP + quad * 8];
    half8 a1 = *(half8*)&sXh[nrow * XP + 32 + quad * 8];

    float bias[4];
#pragma unroll
    for (int j = 0; j < 4; j++) bias[j] = b_l[j * 16 + col16];

    long nodeBase = base + w * 16;

#pragma unroll 2
    for (int ct = 0; ct < 8; ct++) {
        int c = ct * 16 + col16;                 // n = lane&15
        half8 b0 = *(half8*)&sWt[c * XP + quad * 8];
        half8 b1 = *(half8*)&sWt[c * XP + 32 + quad * 8];
        floatx4 acc = {0.f, 0.f, 0.f, 0.f};
        acc = __builtin_amdgcn_mfma_f32_16x16x32_f16(a0, b0, acc, 0, 0, 0);
        acc = __builtin_amdgcn_mfma_f32_16x16x32_f16(a1, b1, acc, 0, 0, 0);

        ushort_t* obuf = (ct < 4) ? y : z;
        int cc    = (ct < 4) ? c : (c - 64);
        float badd = (ct < 4) ? 0.f : bias[ct - 4];
#pragma unroll
        for (int r = 0; r < 4; r++) {
            long node = nodeBase + quad * 4 + r;   // row = quad*4 + reg
            if (node < N) {
                half_t hv = (half_t)(acc[r] + badd);
                obuf[node * D + cc] = *(ushort_t*)&hv;
            }
        }
    }
}

// ---------------------------------------------------------------------------
// Partition pass B: 16 segment-blocks per coarse bucket. Scatters into the 32
// fine buckets inside the coarse bucket. Per-wave privatized histograms;
// padded fcursor (1563 lines) so the 25K global atomics never share a line.
// Repacks src | fineLocal<<17.
// ---------------------------------------------------------------------------
__global__ __launch_bounds__(256) void partB_kernel(
    const unsigned* __restrict__ coarse, const int* __restrict__ ccursor,
    int* __restrict__ fcursor, unsigned* __restrict__ fine)
{
    __shared__ int hist[4][FINE_PER_COARSE];
    __shared__ int wbase[4][FINE_PER_COARSE];
    int cb = blockIdx.x >> 4;        // SEGS = 16
    int seg = blockIdx.x & 15;
    int t = threadIdx.x;
    const int w = t >> 6;

    int cnt = ccursor[cb * CPAD];
    int segLen = (cnt + SEGS - 1) / SEGS;
    int beg = seg * segLen;
    int end = beg + segLen; if (end > cnt) end = cnt;

    if (t < 4 * FINE_PER_COARSE) ((int*)hist)[t] = 0;
    __syncthreads();

    const unsigned* __restrict__ slab = coarse + (size_t)cb * CCAP;

    for (int i = beg + t; i < end; i += 256) {
        unsigned e = slab[i];
        atomicAdd(&hist[w][(e >> 17) >> 6], 1);
    }
    __syncthreads();

    if (t < FINE_PER_COARSE) {
        int c0 = hist[0][t], c1 = hist[1][t];
        int c2 = hist[2][t], c3 = hist[3][t];
        int tot = c0 + c1 + c2 + c3;
        int fb = cb * FINE_PER_COARSE + t;
        int b0 = tot ? atomicAdd(&fcursor[fb * CPAD], tot) : 0;
        wbase[0][t] = b0;
        wbase[1][t] = b0 + c0;
        wbase[2][t] = b0 + c0 + c1;
        wbase[3][t] = b0 + c0 + c1 + c2;
    }
    __syncthreads();

    for (int i = beg + t; i < end; i += 256) {
        unsigned e = slab[i];
        unsigned cl = e >> 17;
        int fb_loc = cl >> 6;
        int pos = atomicSub(&hist[w][fb_loc], 1) - 1;
        size_t fb = (size_t)cb * FINE_PER_COARSE + fb_loc;
        fine[fb * FCAP + wbase[w][fb_loc] + pos] =
            (e & 0x1FFFFu) | ((cl & 63u) << 17);
    }
}

// ---------------------------------------------------------------------------
// Fused sort + gather: one 512-thread block per fine bucket.
// Sort: slab entries staged in registers (<=3/thread), LDS int-atomic
//       counting sort over 64 local nodes; single-wave __shfl_up prefix scan.
// Gather: 8 lanes per node; lane loads uint4 (8 fp16 feats) -> one wave-instr
//       = 8 rows x 128 B. 4-edge unroll for MLP (latency-bound).
// Epilogue: out = tanh(acc + z), z fp16 from ws.
// ---------------------------------------------------------------------------
__global__ __launch_bounds__(512) void sortgather_kernel(
    const ushort_t* __restrict__ y, const ushort_t* __restrict__ z,
    const unsigned* __restrict__ part, const int* __restrict__ cursor,
    float* __restrict__ out, int N)
{
    __shared__ int sorted[SORT_CAP];
    __shared__ int hist[RB];
    __shared__ int cur[RB];
    __shared__ int begL[RB];

    int b = blockIdx.x;
    int t = threadIdx.x;
    int cnt = cursor[b * CPAD];
    if (cnt > SORT_CAP) cnt = SORT_CAP;   // unreachable (max ~950)
    const unsigned* __restrict__ slab = part + (size_t)b * FCAP;

    // stage slab entries in registers (SORT_CAP = 3*512)
    unsigned e0 = 0, e1 = 0, e2 = 0;
    int i0 = t, i1 = t + 512, i2 = t + 1024;
    if (i0 < cnt) e0 = slab[i0];
    if (i1 < cnt) e1 = slab[i1];
    if (i2 < cnt) e2 = slab[i2];

    if (t < RB) hist[t] = 0;
    __syncthreads();

    if (i0 < cnt) atomicAdd(&hist[e0 >> 17], 1);
    if (i1 < cnt) atomicAdd(&hist[e1 >> 17], 1);
    if (i2 < cnt) atomicAdd(&hist[e2 >> 17], 1);
    __syncthreads();

    // exclusive prefix over 64 counters: wave-0 shfl scan, no barriers inside
    if (t < RB) {
        int v = hist[t];
        int inc = v;
#pragma unroll
        for (int off = 1; off < RB; off <<= 1) {
            int n = __shfl_up(inc, off, RB);
            if (t >= off) inc += n;
        }
        int ex = inc - v;
        cur[t] = ex;
        begL[t] = ex;
    }
    __syncthreads();

    if (i0 < cnt) { int p = atomicAdd(&cur[e0 >> 17], 1); sorted[p] = (int)(e0 & 0x1FFFF); }
    if (i1 < cnt) { int p = atomicAdd(&cur[e1 >> 17], 1); sorted[p] = (int)(e1 & 0x1FFFF); }
    if (i2 < cnt) { int p = atomicAdd(&cur[e2 >> 17], 1); sorted[p] = (int)(e2 & 0x1FFFF); }
    __syncthreads();

    // ---- gather phase: group g (8 lanes) owns node g ----
    const int g = t >> 3;     // local node 0..63
    const int f = t & 7;      // feature slice: halves 8f..8f+7
    int myBeg = begL[g];
    int myDeg = hist[g];

    float2 acc0 = make_float2(0.f, 0.f), acc1 = acc0, acc2 = acc0, acc3 = acc0;

    int i = 0;
    for (; i + 4 <= myDeg; i += 4) {
        int s0 = sorted[myBeg + i];
        int s1 = sorted[myBeg + i + 1];
        int s2 = sorted[myBeg + i + 2];
        int s3 = sorted[myBeg + i + 3];
        uint4 r0 = ((const uint4*)(y + (size_t)s0 * D))[f];
        uint4 r1 = ((const uint4*)(y + (size_t)s1 * D))[f];
        uint4 r2 = ((const uint4*)(y + (size_t)s2 * D))[f];
        uint4 r3 = ((const uint4*)(y + (size_t)s3 * D))[f];
#define ACC(r) { \
        float2 c0 = __half22float2(*(const __half2*)&(r).x); \
        float2 c1 = __half22float2(*(const __half2*)&(r).y); \
        float2 c2 = __half22float2(*(const __half2*)&(r).z); \
        float2 c3 = __half22float2(*(const __half2*)&(r).w); \
        acc0.x += c0.x; acc0.y += c0.y; acc1.x += c1.x; acc1.y += c1.y; \
        acc2.x += c2.x; acc2.y += c2.y; acc3.x += c3.x; acc3.y += c3.y; }
        ACC(r0) ACC(r1) ACC(r2) ACC(r3)
    }
    for (; i < myDeg; i++) {
        int s = sorted[myBeg + i];
        uint4 r = ((const uint4*)(y + (size_t)s * D))[f];
        ACC(r)
    }
#undef ACC

    long gn = (long)b * RB + g;
    if (gn < N) {
        uint4 zr = ((const uint4*)(z + (size_t)gn * D))[f];
        float2 z0 = __half22float2(*(const __half2*)&zr.x);
        float2 z1 = __half22float2(*(const __half2*)&zr.y);
        float2 z2 = __half22float2(*(const __half2*)&zr.z);
        float2 z3 = __half22float2(*(const __half2*)&zr.w);
        float4 o0, o1;
        o0.x = tanhf(acc0.x + z0.x); o0.y = tanhf(acc0.y + z0.y);
        o0.z = tanhf(acc1.x + z1.x); o0.w = tanhf(acc1.y + z1.y);
        o1.x = tanhf(acc2.x + z2.x); o1.y = tanhf(acc2.y + z2.y);
        o1.z = tanhf(acc3.x + z3.x); o1.w = tanhf(acc3.y + z3.y);
        float4* op = (float4*)(out + gn * D);
        op[2 * f] = o0;
        op[2 * f + 1] = o1;
    }
}

extern "C" void kernel_launch(void* const* d_in, const int* in_sizes, int n_in,
                              void* d_out, int out_size, void* d_ws, size_t ws_size,
                              hipStream_t stream) {
    const float* x   = (const float*)d_in[0];
    const int* ei    = (const int*)d_in[1];   // [2,E] int32
    const float* W_l = (const float*)d_in[2];
    const float* b_l = (const float*)d_in[3];
    const float* W_r = (const float*)d_in[4];
    float* out = (float*)d_out;

    const int N = N_NODES;
    const int E = N_EDGES;
    const int* src = ei;
    const int* dst = ei + E;

    // workspace layout (ws is 268 MB)
    char* ws = (char*)d_ws;
    ushort_t* y      = (ushort_t*)(ws);                  // 12,800,000 B
    ushort_t* z      = (ushort_t*)(ws + 12800000);       // 12,800,000 B
    unsigned* coarse = (unsigned*)(ws + 25600000);       // NCB*CCAP*4 = 5,619,712 B
    unsigned* fine   = (unsigned*)(ws + 31219712);       // NB*FCAP*4 = 9,603,072 B
    int* ccursor     = (int*)(ws + 40822784);            // 49*64 B = 3,136 B (line-padded)
    int* fcursor     = (int*)(ws + 40825920);            // 1563*64 B = 100,032 B (line-padded)

    // zero both padded cursor arrays (adjacent): 3,136 + 100,032 B
    hipMemsetAsync(ccursor, 0, 103168, stream);

    pre_part_kernel<<<FUSED_BLOCKS, 256, 0, stream>>>(
        x, W_l, b_l, W_r, y, z, src, dst, ccursor, coarse, N, E);
    partB_kernel<<<NCB * SEGS, 256, 0, stream>>>(coarse, ccursor, fcursor, fine);
    sortgather_kernel<<<NB, 512, 0, stream>>>(y, z, fine, fcursor, out, N);
}